// Round 12
// baseline (397.200 us; speedup 1.0000x reference)
//
#include <hip/hip_runtime.h>

#define D_DIM 512

typedef float f32x2 __attribute__((ext_vector_type(2)));

__device__ __forceinline__ float flog2(float x) {
    return __builtin_amdgcn_logf(x);   // v_log_f32 (= log2); inputs >= ~4e-6, no denormal wrapper
}

// ============ per-row sums: E[row] = sum_d x*log2(x). One wave/row, 4 rows/block ============
__global__ __launch_bounds__(256)
void jsd_entropy_kernel(const float* __restrict__ a,
                        const float* __restrict__ b,
                        float* __restrict__ E, int N, int M) {
    const int wave = threadIdx.x >> 6;
    const int lane = threadIdx.x & 63;
    const int row = blockIdx.x * 4 + wave;
    if (row >= N + M) return;
    const float* src = (row < N) ? (a + (size_t)row * D_DIM)
                                 : (b + (size_t)(row - N) * D_DIM);
    const float4* s4 = (const float4*)src;
    float4 v0 = s4[lane];
    float4 v1 = s4[lane + 64];
    float s = 0.f;
    s = fmaf(v0.x, flog2(v0.x), s);
    s = fmaf(v0.y, flog2(v0.y), s);
    s = fmaf(v0.z, flog2(v0.z), s);
    s = fmaf(v0.w, flog2(v0.w), s);
    s = fmaf(v1.x, flog2(v1.x), s);
    s = fmaf(v1.y, flog2(v1.y), s);
    s = fmaf(v1.z, flog2(v1.z), s);
    s = fmaf(v1.w, flog2(v1.w), s);
#pragma unroll
    for (int off = 32; off > 0; off >>= 1) s += __shfl_down(s, off, 64);
    if (lane == 0) E[row] = s;
}

// ============ main ============
// out[i,j] = 1 + 0.5*(Ea[i]+Eb[j]) - 0.5*sum_d t*log2(t), t = a_i[d]+b_j[d]
//
// R11 wave (32x16 tile, 4x2 per lane, 4 independent d-quarter waves, no main-
// loop barrier) with LDS squeezed to 16 KB/block -> 8 blocks/CU = 8 INDEPENDENT
// waves/SIMD (thread-cap exact). A staged per 8-d chunk (1 GLDS, dbuf 2 KB/
// wave); B per 16-d pair (1 GLDS, dbuf 2 KB/wave). Permuted stage layouts keep
// GLDS linear while reads are base+imm and bank-conflict-free:
//   A: lane l fetches (row 4(l&7)+(l>>4), slot (l>>3)&1); read p = LR+8(2i+q)
//   B: lane l fetches (row 2(l&7)+(l>>5), slot (l>>3)&3); read p = LC+8(4c+2h+q)
// launch_bounds(256,8): 64-reg cap — single load-set body ~56 regs fits (R11
// measured 48 for the same shape). Cap deliberately blocks ILP-pipelining; the
// bet is TLP (8 waves) covers per-q lgkm stalls.
// Closed levers: 4x4@8-blocks (R5 spill at 64-cap: needs ~80), region pinning
// (R7 spill), asm ds pipeline (R8 NaN), entropy fusion (R10 +10us).
constexpr int TR  = 32;          // A-rows per block
constexpr int TC  = 16;          // B-cols per block
constexpr int NCH = 16;          // 8-d chunks per 128-d wave quarter

#define GLDS(gp, lp)                                                           \
    __builtin_amdgcn_global_load_lds(                                          \
        (const __attribute__((address_space(1))) void*)(gp),                   \
        (__attribute__((address_space(3))) void*)(lp), 16, 0, 0)

__global__ __launch_bounds__(256, 8)
void jsd_main_kernel(const float* __restrict__ a, const float* __restrict__ b,
                     const float* __restrict__ Ea, const float* __restrict__ Eb,
                     float* __restrict__ out, int N, int M) {
    __shared__ __align__(16) float ldsA[4][2][256];   // [wave][buf][pos] = 8 KB
    __shared__ __align__(16) float ldsB[4][2][256];   // 8 KB

    const int tid = threadIdx.x;
    const int w   = tid >> 6;        // wave = d-quarter
    const int l   = tid & 63;
    const int LR  = l >> 3;          // lane row group (0..7): rows 4*LR..+3
    const int LC  = l & 7;           // lane col group (0..7): cols 2*LC..+1
    const int rowBase = blockIdx.y * TR;
    const int colBase = blockIdx.x * TC;

    // permuted staging: lane l -> (row, 16B slot); LDS dest stays linear
    const int rA = 4 * (l & 7) + (l >> 4);   // A row this lane stages
    const int cA = (l >> 3) & 1;             // A slot within 8-d chunk
    const int rB = 2 * (l & 7) + (l >> 5);   // B row this lane stages
    const int sB = (l >> 3) & 3;             // B slot within 16-d pair
    const float* gA = a + (size_t)(rowBase + rA) * D_DIM + w * 128 + cA * 4;
    const float* gB = b + (size_t)(colBase + rB) * D_DIM + w * 128 + sB * 4;

    float* A0 = &ldsA[w][0][0];      // GLDS dests (wave-uniform)
    float* A1 = &ldsA[w][1][0];
    float* Bd0 = &ldsB[w][0][0];
    float* Bd1 = &ldsB[w][1][0];
    const float* Ar0 = A0 + 4 * LR;  // read bases: everything else is imm
    const float* Ar1 = A1 + 4 * LR;
    const float* Br0 = Bd0 + 4 * LC;
    const float* Br1 = Bd1 + 4 * LC;

    f32x2 acc2[4][2];
#pragma unroll
    for (int i = 0; i < 4; ++i)
#pragma unroll
        for (int j = 0; j < 2; ++j) acc2[i][j] = (f32x2){0.f, 0.f};

    GLDS(gA, A0);          // A chunk 0
    GLDS(gB, Bd0);         // B chunks 0-1

#define LOADQ(qc, hc, AR, BR)                                                  \
    do {                                                                       \
        _Pragma("unroll") for (int i_ = 0; i_ < 4; ++i_)                       \
            av[i_] = *(const float4*)&AR[32 * (2 * i_ + (qc))];                \
        _Pragma("unroll") for (int c_ = 0; c_ < 2; ++c_)                       \
            bv[c_] = *(const float4*)&BR[32 * (4 * c_ + 2 * (hc) + (qc))];     \
    } while (0)

#define COMPQ()                                                                \
    do {                                                                       \
        _Pragma("unroll") for (int rr_ = 0; rr_ < 4; ++rr_) {                  \
            const f32x2 a0_ = {av[rr_].x, av[rr_].y};                          \
            const f32x2 a1_ = {av[rr_].z, av[rr_].w};                          \
            _Pragma("unroll") for (int cc_ = 0; cc_ < 2; ++cc_) {              \
                f32x2 t0_ = a0_ + (f32x2){bv[cc_].x, bv[cc_].y};               \
                f32x2 t1_ = a1_ + (f32x2){bv[cc_].z, bv[cc_].w};               \
                f32x2 l0_ = {flog2(t0_.x), flog2(t0_.y)};                      \
                f32x2 l1_ = {flog2(t1_.x), flog2(t1_.y)};                      \
                acc2[rr_][cc_] = __builtin_elementwise_fma(t0_, l0_, acc2[rr_][cc_]); \
                acc2[rr_][cc_] = __builtin_elementwise_fma(t1_, l1_, acc2[rr_][cc_]); \
            }                                                                  \
        }                                                                      \
    } while (0)

#define CHUNK(AR, BR, hc)                                                      \
    do {                                                                       \
        LOADQ(0, hc, AR, BR); COMPQ();                                         \
        LOADQ(1, hc, AR, BR); COMPQ();                                         \
    } while (0)

#define WAITSTAGE() asm volatile("s_waitcnt vmcnt(0)" ::: "memory")
#define SBAR()      __builtin_amdgcn_sched_barrier(0)

    float4 av[4], bv[2];

    // 4 chunks per iteration -> all buffer selects compile-time, no ptr swaps.
    // Invariant at loop top: A[ck]->A0 and B[ck,ck+1]->Bd0 in flight.
#pragma unroll 1
    for (int ck = 0; ck < NCH; ck += 4) {
        WAITSTAGE();                                    // A[ck], B[ck,ck+1] landed
        gA += 8; GLDS(gA, A1);                          // stage A[ck+1]
        SBAR();
        CHUNK(Ar0, Br0, 0);                             // chunk ck

        WAITSTAGE();                                    // A[ck+1] landed
        gA += 8;  GLDS(gA, A0);                         // stage A[ck+2]
        gB += 16; GLDS(gB, Bd1);                        // stage B[ck+2,ck+3]
        SBAR();
        CHUNK(Ar1, Br0, 1);                             // chunk ck+1

        WAITSTAGE();                                    // A[ck+2], B[ck+2,ck+3] landed
        gA += 8; GLDS(gA, A1);                          // stage A[ck+3]
        SBAR();
        CHUNK(Ar0, Br1, 0);                             // chunk ck+2

        WAITSTAGE();                                    // A[ck+3] landed
        if (ck + 4 < NCH) {
            gA += 8;  GLDS(gA, A0);                     // stage A[ck+4]
            gB += 16; GLDS(gB, Bd0);                    // stage B[ck+4,ck+5]
        }
        SBAR();
        CHUNK(Ar1, Br1, 1);                             // chunk ck+3
    }
#undef CHUNK
#undef COMPQ
#undef LOADQ
#undef WAITSTAGE
#undef SBAR

    // -------- 4-way d-merge via LDS (two barriers, no atomics) --------
    float accs[8];
#pragma unroll
    for (int i = 0; i < 8; ++i) accs[i] = acc2[i >> 1][i & 1].x + acc2[i >> 1][i & 1].y;

    __syncthreads();                   // everyone done reading their LDS slices
    float* scratch = &ldsA[0][0][0];   // 2048 floats; need 4*8*64 = 2048 exactly
#pragma unroll
    for (int i = 0; i < 8; ++i)
        scratch[(w * 8 + i) * 64 + l] = accs[i];   // banks = l%32: 2-way (free)
    __syncthreads();

    // thread (w,l) combines + stores (row 4*LR+w, cols 2*LC..2*LC+1)
    float s0 = 0.f, s1 = 0.f;
#pragma unroll
    for (int w2 = 0; w2 < 4; ++w2) {
        s0 += scratch[(w2 * 8 + 2 * w + 0) * 64 + l];
        s1 += scratch[(w2 * 8 + 2 * w + 1) * 64 + l];
    }
    const int row = rowBase + 4 * LR + w;
    const int col = colBase + 2 * LC;
    const float eav = Ea[row];
    const float2 eb = *(const float2*)&Eb[col];
    const float base_v = 1.0f + 0.5f * eav;
    float2 v;
    v.x = fmaf(-0.5f, s0, base_v + 0.5f * eb.x);
    v.y = fmaf(-0.5f, s1, base_v + 0.5f * eb.y);
    *(float2*)(out + (size_t)row * M + col) = v;
}

extern "C" void kernel_launch(void* const* d_in, const int* in_sizes, int n_in,
                              void* d_out, int out_size, void* d_ws, size_t ws_size,
                              hipStream_t stream) {
    const float* a = (const float*)d_in[0];
    const float* b = (const float*)d_in[1];
    const int N = in_sizes[0] / D_DIM;   // 1024
    const int M = in_sizes[1] / D_DIM;   // 1024
    float* E = (float*)d_ws;             // Ea[0..N), Eb[N..N+M)

    jsd_entropy_kernel<<<(N + M + 3) / 4, 256, 0, stream>>>(a, b, E, N, M);

    dim3 grid(M / TC, N / TR);           // 64 x 32 = 2048 blocks -> 8 blocks/CU
    jsd_main_kernel<<<grid, 256, 0, stream>>>(a, b, E, E + N, (float*)d_out, N, M);
}

// Round 13
// 187.451 us; speedup vs baseline: 2.1189x; 2.1189x over previous
//
#include <hip/hip_runtime.h>

#define D_DIM 512

typedef float f32x2 __attribute__((ext_vector_type(2)));

__device__ __forceinline__ float flog2(float x) {
    return __builtin_amdgcn_logf(x);   // v_log_f32 (= log2); inputs >= ~4e-6, no denormal wrapper
}

// ============ per-row sums: E[row] = sum_d x*log2(x). One wave/row, 4 rows/block ============
__global__ __launch_bounds__(256)
void jsd_entropy_kernel(const float* __restrict__ a,
                        const float* __restrict__ b,
                        float* __restrict__ E, int N, int M) {
    const int wave = threadIdx.x >> 6;
    const int lane = threadIdx.x & 63;
    const int row = blockIdx.x * 4 + wave;
    if (row >= N + M) return;
    const float* src = (row < N) ? (a + (size_t)row * D_DIM)
                                 : (b + (size_t)(row - N) * D_DIM);
    const float4* s4 = (const float4*)src;
    float4 v0 = s4[lane];
    float4 v1 = s4[lane + 64];
    float s = 0.f;
    s = fmaf(v0.x, flog2(v0.x), s);
    s = fmaf(v0.y, flog2(v0.y), s);
    s = fmaf(v0.z, flog2(v0.z), s);
    s = fmaf(v0.w, flog2(v0.w), s);
    s = fmaf(v1.x, flog2(v1.x), s);
    s = fmaf(v1.y, flog2(v1.y), s);
    s = fmaf(v1.z, flog2(v1.z), s);
    s = fmaf(v1.w, flog2(v1.w), s);
#pragma unroll
    for (int off = 32; off > 0; off >>= 1) s += __shfl_down(s, off, 64);
    if (lane == 0) E[row] = s;
}

// ============ main ============
// out[i,j] = 1 + 0.5*(Ea[i]+Eb[j]) - 0.5*sum_d t*log2(t), t = a_i[d]+b_j[d]
//
// R12 structure (32x16 tile, 4x2 per lane, 4 independent d-quarter waves, no
// main-loop barrier, 16 KB LDS/block) with NATURAL register allocation
// (launch_bounds(256,4), cap 128). 16 KB -> LDS-cap 10 blocks/CU; thread-cap
// 8; if VGPR lands <=64 (R11's near-identical body: 48) the HW gives
// 8 blocks/CU = 8 INDEPENDENT waves/SIMD with zero spill.
// A staged per 8-d chunk (1 GLDS, dbuf 2 KB/wave); B per 16-d pair (1 GLDS,
// dbuf 2 KB/wave). Permuted stage layouts keep GLDS linear, reads base+imm,
// bank-conflict-free:
//   A: lane l fetches (row 4(l&7)+(l>>4), slot (l>>3)&1); read p = LR+8(2i+q)
//   B: lane l fetches (row 2(l&7)+(l>>5), slot (l>>3)&3); read p = LC+8(4c+2h+q)
// Closed levers (do not revisit): EXPLICIT 64-reg cap (R5+R12: spills, 0.8-1 GB
// scratch traffic), sched_barrier region pinning (R7 spill), inline-asm ds_read
// pipeline (R8 NaN), entropy fusion (R10: +10us kernel, -4us overhead).
constexpr int TR  = 32;          // A-rows per block
constexpr int TC  = 16;          // B-cols per block
constexpr int NCH = 16;          // 8-d chunks per 128-d wave quarter

#define GLDS(gp, lp)                                                           \
    __builtin_amdgcn_global_load_lds(                                          \
        (const __attribute__((address_space(1))) void*)(gp),                   \
        (__attribute__((address_space(3))) void*)(lp), 16, 0, 0)

__global__ __launch_bounds__(256, 4)
void jsd_main_kernel(const float* __restrict__ a, const float* __restrict__ b,
                     const float* __restrict__ Ea, const float* __restrict__ Eb,
                     float* __restrict__ out, int N, int M) {
    __shared__ __align__(16) float ldsA[4][2][256];   // [wave][buf][pos] = 8 KB
    __shared__ __align__(16) float ldsB[4][2][256];   // 8 KB

    const int tid = threadIdx.x;
    const int w   = tid >> 6;        // wave = d-quarter
    const int l   = tid & 63;
    const int LR  = l >> 3;          // lane row group (0..7): rows 4*LR..+3
    const int LC  = l & 7;           // lane col group (0..7): cols 2*LC..+1
    const int rowBase = blockIdx.y * TR;
    const int colBase = blockIdx.x * TC;

    // permuted staging: lane l -> (row, 16B slot); LDS dest stays linear
    const int rA = 4 * (l & 7) + (l >> 4);   // A row this lane stages
    const int cA = (l >> 3) & 1;             // A slot within 8-d chunk
    const int rB = 2 * (l & 7) + (l >> 5);   // B row this lane stages
    const int sB = (l >> 3) & 3;             // B slot within 16-d pair
    const float* gA = a + (size_t)(rowBase + rA) * D_DIM + w * 128 + cA * 4;
    const float* gB = b + (size_t)(colBase + rB) * D_DIM + w * 128 + sB * 4;

    float* A0 = &ldsA[w][0][0];      // GLDS dests (wave-uniform)
    float* A1 = &ldsA[w][1][0];
    float* Bd0 = &ldsB[w][0][0];
    float* Bd1 = &ldsB[w][1][0];
    const float* Ar0 = A0 + 4 * LR;  // read bases: everything else is imm
    const float* Ar1 = A1 + 4 * LR;
    const float* Br0 = Bd0 + 4 * LC;
    const float* Br1 = Bd1 + 4 * LC;

    f32x2 acc2[4][2];
#pragma unroll
    for (int i = 0; i < 4; ++i)
#pragma unroll
        for (int j = 0; j < 2; ++j) acc2[i][j] = (f32x2){0.f, 0.f};

    GLDS(gA, A0);          // A chunk 0
    GLDS(gB, Bd0);         // B chunks 0-1

#define LOADQ(qc, hc, AR, BR)                                                  \
    do {                                                                       \
        _Pragma("unroll") for (int i_ = 0; i_ < 4; ++i_)                       \
            av[i_] = *(const float4*)&AR[32 * (2 * i_ + (qc))];                \
        _Pragma("unroll") for (int c_ = 0; c_ < 2; ++c_)                       \
            bv[c_] = *(const float4*)&BR[32 * (4 * c_ + 2 * (hc) + (qc))];     \
    } while (0)

#define COMPQ()                                                                \
    do {                                                                       \
        _Pragma("unroll") for (int rr_ = 0; rr_ < 4; ++rr_) {                  \
            const f32x2 a0_ = {av[rr_].x, av[rr_].y};                          \
            const f32x2 a1_ = {av[rr_].z, av[rr_].w};                          \
            _Pragma("unroll") for (int cc_ = 0; cc_ < 2; ++cc_) {              \
                f32x2 t0_ = a0_ + (f32x2){bv[cc_].x, bv[cc_].y};               \
                f32x2 t1_ = a1_ + (f32x2){bv[cc_].z, bv[cc_].w};               \
                f32x2 l0_ = {flog2(t0_.x), flog2(t0_.y)};                      \
                f32x2 l1_ = {flog2(t1_.x), flog2(t1_.y)};                      \
                acc2[rr_][cc_] = __builtin_elementwise_fma(t0_, l0_, acc2[rr_][cc_]); \
                acc2[rr_][cc_] = __builtin_elementwise_fma(t1_, l1_, acc2[rr_][cc_]); \
            }                                                                  \
        }                                                                      \
    } while (0)

#define CHUNK(AR, BR, hc)                                                      \
    do {                                                                       \
        LOADQ(0, hc, AR, BR); COMPQ();                                         \
        LOADQ(1, hc, AR, BR); COMPQ();                                         \
    } while (0)

#define WAITSTAGE() asm volatile("s_waitcnt vmcnt(0)" ::: "memory")
#define SBAR()      __builtin_amdgcn_sched_barrier(0)

    float4 av[4], bv[2];

    // 4 chunks per iteration -> all buffer selects compile-time, no ptr swaps.
    // Invariant at loop top: A[ck]->A0 and B[ck,ck+1]->Bd0 in flight.
#pragma unroll 1
    for (int ck = 0; ck < NCH; ck += 4) {
        WAITSTAGE();                                    // A[ck], B[ck,ck+1] landed
        gA += 8; GLDS(gA, A1);                          // stage A[ck+1]
        SBAR();
        CHUNK(Ar0, Br0, 0);                             // chunk ck

        WAITSTAGE();                                    // A[ck+1] landed
        gA += 8;  GLDS(gA, A0);                         // stage A[ck+2]
        gB += 16; GLDS(gB, Bd1);                        // stage B[ck+2,ck+3]
        SBAR();
        CHUNK(Ar1, Br0, 1);                             // chunk ck+1

        WAITSTAGE();                                    // A[ck+2], B[ck+2,ck+3] landed
        gA += 8; GLDS(gA, A1);                          // stage A[ck+3]
        SBAR();
        CHUNK(Ar0, Br1, 0);                             // chunk ck+2

        WAITSTAGE();                                    // A[ck+3] landed
        if (ck + 4 < NCH) {
            gA += 8;  GLDS(gA, A0);                     // stage A[ck+4]
            gB += 16; GLDS(gB, Bd0);                    // stage B[ck+4,ck+5]
        }
        SBAR();
        CHUNK(Ar1, Br1, 1);                             // chunk ck+3
    }
#undef CHUNK
#undef COMPQ
#undef LOADQ
#undef WAITSTAGE
#undef SBAR

    // -------- 4-way d-merge via LDS (two barriers, no atomics) --------
    float accs[8];
#pragma unroll
    for (int i = 0; i < 8; ++i) accs[i] = acc2[i >> 1][i & 1].x + acc2[i >> 1][i & 1].y;

    __syncthreads();                   // everyone done reading their LDS slices
    float* scratch = &ldsA[0][0][0];   // 2048 floats; need 4*8*64 = 2048 exactly
#pragma unroll
    for (int i = 0; i < 8; ++i)
        scratch[(w * 8 + i) * 64 + l] = accs[i];   // banks = l%32: 2-way (free)
    __syncthreads();

    // thread (w,l) combines + stores (row 4*LR+w, cols 2*LC..2*LC+1)
    float s0 = 0.f, s1 = 0.f;
#pragma unroll
    for (int w2 = 0; w2 < 4; ++w2) {
        s0 += scratch[(w2 * 8 + 2 * w + 0) * 64 + l];
        s1 += scratch[(w2 * 8 + 2 * w + 1) * 64 + l];
    }
    const int row = rowBase + 4 * LR + w;
    const int col = colBase + 2 * LC;
    const float eav = Ea[row];
    const float2 eb = *(const float2*)&Eb[col];
    const float base_v = 1.0f + 0.5f * eav;
    float2 v;
    v.x = fmaf(-0.5f, s0, base_v + 0.5f * eb.x);
    v.y = fmaf(-0.5f, s1, base_v + 0.5f * eb.y);
    *(float2*)(out + (size_t)row * M + col) = v;
}

extern "C" void kernel_launch(void* const* d_in, const int* in_sizes, int n_in,
                              void* d_out, int out_size, void* d_ws, size_t ws_size,
                              hipStream_t stream) {
    const float* a = (const float*)d_in[0];
    const float* b = (const float*)d_in[1];
    const int N = in_sizes[0] / D_DIM;   // 1024
    const int M = in_sizes[1] / D_DIM;   // 1024
    float* E = (float*)d_ws;             // Ea[0..N), Eb[N..N+M)

    jsd_entropy_kernel<<<(N + M + 3) / 4, 256, 0, stream>>>(a, b, E, N, M);

    dim3 grid(M / TC, N / TR);           // 64 x 32 = 2048 blocks -> 8 blocks/CU (LDS: 10, threads: 8)
    jsd_main_kernel<<<grid, 256, 0, stream>>>(a, b, E, E + N, (float*)d_out, N, M);
}

// Round 15
// 106.622 us; speedup vs baseline: 3.7253x; 1.7581x over previous
//
#include <hip/hip_runtime.h>

#define D_DIM 512

typedef float f32x2 __attribute__((ext_vector_type(2)));

__device__ __forceinline__ float flog2(float x) {
    return __builtin_amdgcn_logf(x);   // v_log_f32 (= log2); inputs >= ~4e-6, no denormal wrapper
}

// ============ per-row sums: E[row] = sum_d x*log2(x). One wave/row, 4 rows/block ============
__global__ __launch_bounds__(256)
void jsd_entropy_kernel(const float* __restrict__ a,
                        const float* __restrict__ b,
                        float* __restrict__ E, int N, int M) {
    const int wave = threadIdx.x >> 6;
    const int lane = threadIdx.x & 63;
    const int row = blockIdx.x * 4 + wave;
    if (row >= N + M) return;
    const float* src = (row < N) ? (a + (size_t)row * D_DIM)
                                 : (b + (size_t)(row - N) * D_DIM);
    const float4* s4 = (const float4*)src;
    float4 v0 = s4[lane];
    float4 v1 = s4[lane + 64];
    float s = 0.f;
    s = fmaf(v0.x, flog2(v0.x), s);
    s = fmaf(v0.y, flog2(v0.y), s);
    s = fmaf(v0.z, flog2(v0.z), s);
    s = fmaf(v0.w, flog2(v0.w), s);
    s = fmaf(v1.x, flog2(v1.x), s);
    s = fmaf(v1.y, flog2(v1.y), s);
    s = fmaf(v1.z, flog2(v1.z), s);
    s = fmaf(v1.w, flog2(v1.w), s);
#pragma unroll
    for (int off = 32; off > 0; off >>= 1) s += __shfl_down(s, off, 64);
    if (lane == 0) E[row] = s;
}

// ============ main ============
// out[i,j] = 1 + 0.5*(Ea[i]+Eb[j]) - 0.5*sum_d t*log2(t), t = a_i[d]+b_j[d]
//
// FINAL (R11, best total 104.98 us; R14 bench was an infra failure, resubmit):
// 32x16 tile, 4x2 per lane, 4 INDEPENDENT d-quarter waves, no main-loop
// barrier. Wave-private LDS, double-buffered global_load_lds, own vmcnt.
// 24 KB LDS/block -> 6 blocks/CU = 6 independent waves/SIMD; VGPR 48 natural,
// zero spill.
//
// Session ledger (13 measured rounds):
// - Busy floor ~41 us/SIMD: logs 27 us (v_log quarter-rate, issue-blocking,
//   irreducible), pk_add/pk_fma 7 us (packed f32 halved this), overhead ~6.
// - Best mains 57.6-59.0 us = floor/~0.72; the ~28% idle resisted every lever:
//   * 8 waves/SIMD: body needs >64 VGPR -> spills (R12 explicit cap, R13
//     backend LDS-driven occupancy heuristic; 0.4-1 GB scratch traffic).
//     2x2 blocking fits 64 but doubles LDS-read issue (R2: 73 us). Closed.
//   * compiler-visible SW pipelining: scheduler sinks loads (R6, VGPR 52).
//   * sched_barrier region pinning: regalloc spill (R7).
//   * inline-asm ds_read pipeline: regalloc copy race -> NaN (R8).
//   * entropy fusion: +10 us kernel for -4 us overhead (R10).
// - Harness-fixed overhead ~45 us (launch/graph/sync), source-unreachable.
constexpr int TR  = 32;          // A-rows per block
constexpr int TC  = 16;          // B-cols per block
constexpr int DK  = 16;          // d per chunk (row = 64 B in LDS, 4 float4 slots)
constexpr int QD  = 128;         // d per wave (quarter)
constexpr int NCH = QD / DK;     // 8

#define GLDS(gp, lp)                                                           \
    __builtin_amdgcn_global_load_lds(                                          \
        (const __attribute__((address_space(1))) void*)(gp),                   \
        (__attribute__((address_space(3))) void*)(lp), 16, 0, 0)

__global__ __launch_bounds__(256, 4)
void jsd_main_kernel(const float* __restrict__ a, const float* __restrict__ b,
                     const float* __restrict__ Ea, const float* __restrict__ Eb,
                     float* __restrict__ out, int N, int M) {
    // per wave-buf: A = 32x16 floats @0, B = 16x16 floats @512 -> 768 floats
    __shared__ __align__(16) float lds[4][2][768];   // 24 KB

    const int tid = threadIdx.x;
    const int w   = tid >> 6;        // wave = d-quarter
    const int l   = tid & 63;
    const int lr  = l >> 3;          // lane row group (0..7): rows 4*lr..4*lr+3
    const int lc  = l & 7;           // lane col group (0..7): cols 2*lc..2*lc+1
    const int rowBase = blockIdx.y * TR;
    const int colBase = blockIdx.x * TC;

    // Hoisted per-lane swizzled staging source (LDS dest linear, source slot =
    // (l&3) ^ ((row>>2)&3); swizzle value == (l>>4)&3 for both 16-row halves).
    const int srow = l >> 2;                            // 0..15
    const int scol = 4 * ((l & 3) ^ ((l >> 4) & 3));    // swizzled 16B slot
    const float* gA = a + (size_t)(rowBase + srow) * D_DIM + w * QD + scol;
    const float* gB = b + (size_t)(colBase + srow) * D_DIM + w * QD + scol;

    float* A0 = &lds[w][0][0];
    float* B0 = A0 + 512;
    float* A1 = &lds[w][1][0];
    float* B1 = A1 + 512;

    f32x2 acc2[4][2];
#pragma unroll
    for (int i = 0; i < 4; ++i)
#pragma unroll
        for (int j = 0; j < 2; ++j) acc2[i][j] = (f32x2){0.f, 0.f};

    // chunk 0: A rows 0-15, rows 16-31, B rows 0-15 (one GLDS each)
    GLDS(gA, A0); GLDS(gA + 16 * D_DIM, A0 + 256); GLDS(gB, B0);

#define LOADQ(qc, BUFA, BUFB, AV, BV)                                          \
    do {                                                                       \
        const int sa_ = (((qc) ^ lr) & 3) << 2;                                \
        const int sb_ = (((qc) ^ (lc >> 1)) & 3) << 2;                         \
        _Pragma("unroll") for (int i_ = 0; i_ < 4; ++i_)                       \
            AV[i_] = *(const float4*)&BUFA[(4 * lr + i_) * DK + sa_];          \
        _Pragma("unroll") for (int c_ = 0; c_ < 2; ++c_)                       \
            BV[c_] = *(const float4*)&BUFB[(2 * lc + c_) * DK + sb_];          \
    } while (0)

#define COMPQ(AV, BV)                                                          \
    do {                                                                       \
        _Pragma("unroll") for (int rr_ = 0; rr_ < 4; ++rr_) {                  \
            const f32x2 a0_ = {AV[rr_].x, AV[rr_].y};                          \
            const f32x2 a1_ = {AV[rr_].z, AV[rr_].w};                          \
            _Pragma("unroll") for (int cc_ = 0; cc_ < 2; ++cc_) {              \
                f32x2 t0_ = a0_ + (f32x2){BV[cc_].x, BV[cc_].y};               \
                f32x2 t1_ = a1_ + (f32x2){BV[cc_].z, BV[cc_].w};               \
                f32x2 l0_ = {flog2(t0_.x), flog2(t0_.y)};                      \
                f32x2 l1_ = {flog2(t1_.x), flog2(t1_.y)};                      \
                acc2[rr_][cc_] = __builtin_elementwise_fma(t0_, l0_, acc2[rr_][cc_]); \
                acc2[rr_][cc_] = __builtin_elementwise_fma(t1_, l1_, acc2[rr_][cc_]); \
            }                                                                  \
        }                                                                      \
    } while (0)

// software-pipelined q loop (compiler-scheduled)
#define CHUNK(AW, BW)                                                          \
    do {                                                                       \
        LOADQ(0, AW, BW, avA, bvA);                                            \
        LOADQ(1, AW, BW, avB, bvB);                                            \
        COMPQ(avA, bvA);                                                       \
        LOADQ(2, AW, BW, avA, bvA);                                            \
        COMPQ(avB, bvB);                                                       \
        LOADQ(3, AW, BW, avB, bvB);                                            \
        COMPQ(avA, bvA);                                                       \
        COMPQ(avB, bvB);                                                       \
    } while (0)

#define WAITSTAGE() asm volatile("s_waitcnt vmcnt(0)" ::: "memory")

    float4 avA[4], bvA[2], avB[4], bvB[2];

#pragma unroll 1
    for (int ck = 0; ck < NCH - 2; ck += 2) {
        WAITSTAGE();                                   // buf0 chunk landed
        gA += DK; gB += DK;
        GLDS(gA, A1); GLDS(gA + 16 * D_DIM, A1 + 256); GLDS(gB, B1);  // -> buf1
        __builtin_amdgcn_sched_barrier(0);             // keep load-issue ahead of compute
        CHUNK(A0, B0);

        WAITSTAGE();                                   // buf1 chunk landed
        gA += DK; gB += DK;
        GLDS(gA, A0); GLDS(gA + 16 * D_DIM, A0 + 256); GLDS(gB, B0);  // -> buf0
        __builtin_amdgcn_sched_barrier(0);
        CHUNK(A1, B1);
    }
    // peeled tail
    WAITSTAGE();
    gA += DK; gB += DK;
    GLDS(gA, A1); GLDS(gA + 16 * D_DIM, A1 + 256); GLDS(gB, B1);
    __builtin_amdgcn_sched_barrier(0);
    CHUNK(A0, B0);
    WAITSTAGE();
    CHUNK(A1, B1);

#undef CHUNK
#undef COMPQ
#undef LOADQ
#undef WAITSTAGE

    // -------- 4-way d-merge via LDS (two barriers, no atomics) --------
    float accs[8];
#pragma unroll
    for (int i = 0; i < 8; ++i) accs[i] = acc2[i >> 1][i & 1].x + acc2[i >> 1][i & 1].y;

    __syncthreads();                   // everyone done reading their LDS slice
    float* scratch = &lds[0][0][0];    // 6144 floats; need 4*8*65 = 2080
#pragma unroll
    for (int i = 0; i < 8; ++i)
        scratch[(w * 8 + i) * 65 + l] = accs[i];   // stride 65: conflict-free
    __syncthreads();

    // thread (w,l) combines + stores (row 4*lr+w, cols 2*lc..2*lc+1)
    float s0 = 0.f, s1 = 0.f;
#pragma unroll
    for (int w2 = 0; w2 < 4; ++w2) {
        s0 += scratch[(w2 * 8 + 2 * w + 0) * 65 + l];
        s1 += scratch[(w2 * 8 + 2 * w + 1) * 65 + l];
    }
    const int row = rowBase + 4 * lr + w;
    const int col = colBase + 2 * lc;
    const float eav = Ea[row];
    const float2 eb = *(const float2*)&Eb[col];
    const float base_v = 1.0f + 0.5f * eav;
    float2 v;
    v.x = fmaf(-0.5f, s0, base_v + 0.5f * eb.x);
    v.y = fmaf(-0.5f, s1, base_v + 0.5f * eb.y);
    *(float2*)(out + (size_t)row * M + col) = v;
}

extern "C" void kernel_launch(void* const* d_in, const int* in_sizes, int n_in,
                              void* d_out, int out_size, void* d_ws, size_t ws_size,
                              hipStream_t stream) {
    const float* a = (const float*)d_in[0];
    const float* b = (const float*)d_in[1];
    const int N = in_sizes[0] / D_DIM;   // 1024
    const int M = in_sizes[1] / D_DIM;   // 1024
    float* E = (float*)d_ws;             // Ea[0..N), Eb[N..N+M)

    jsd_entropy_kernel<<<(N + M + 3) / 4, 256, 0, stream>>>(a, b, E, N, M);

    dim3 grid(M / TC, N / TR);           // 64 x 32 = 2048 blocks -> 6 blocks/CU (LDS-limited)
    jsd_main_kernel<<<grid, 256, 0, stream>>>(a, b, E, E + N, (float*)d_out, N, M);
}